// Round 11
// baseline (160.783 us; speedup 1.0000x reference)
//
#include <hip/hip_runtime.h>
#include <math.h>

#define BB   128
#define TT   64
#define IND  128
#define HID  256
#define CD   384   // comb dim = IND + HID

struct C2 { float x, y; };
__device__ __forceinline__ C2 cmul(C2 a, C2 b) { return {a.x*b.x - a.y*b.y, a.x*b.y + a.y*b.x}; }
__device__ __forceinline__ C2 cadd(C2 a, C2 b) { return {a.x + b.x, a.y + b.y}; }
__device__ __forceinline__ C2 csub(C2 a, C2 b) { return {a.x - b.x, a.y - b.y}; }
__device__ __forceinline__ C2 conjc(C2 a) { return {a.x, -a.y}; }

struct Args {
    const float* x;
    const float* W[4];
    const float* bb[4];
    const float* qp[4];
    const float* Uo[4];
    const float* cb[4];
    float* out;
};

template<int CTRL>
__device__ __forceinline__ int dppmv(int v) {
    return __builtin_amdgcn_update_dpp(v, v, CTRL, 0xF, 0xF, false);
}

// Lane-xor exchange (R9/R10-proven, all-VALU).
template<int M>
__device__ __forceinline__ float lx(float v) {
    int i = __float_as_int(v);
    if constexpr (M == 1)
        return __int_as_float(dppmv<0xB1>(i));            // quad_perm [1,0,3,2]
    else if constexpr (M == 2)
        return __int_as_float(dppmv<0x4E>(i));            // quad_perm [2,3,0,1]
    else if constexpr (M == 4) {
        int a = dppmv<0x104>(i);                          // row_shl:4
        int b = dppmv<0x114>(i);                          // row_shr:4
        return __int_as_float((threadIdx.x & 4) ? b : a);
    } else if constexpr (M == 8)
        return __int_as_float(dppmv<0x128>(i));           // row_ror:8 == xor8
    else if constexpr (M == 16) {
#if __has_builtin(__builtin_amdgcn_permlane16_swap)
        auto r = __builtin_amdgcn_permlane16_swap(i, i, false, false);
        return __int_as_float((threadIdx.x & 16) ? r[0] : r[1]);
#else
        return __int_as_float(__builtin_amdgcn_ds_swizzle(i, 0x401F));
#endif
    } else {
#if __has_builtin(__builtin_amdgcn_permlane32_swap)
        auto r = __builtin_amdgcn_permlane32_swap(i, i, false, false);
        return __int_as_float((threadIdx.x & 32) ? r[0] : r[1]);
#else
        return __shfl_xor(v, 32);
#endif
    }
}

__device__ __forceinline__ float rfl(float v) {
    return __int_as_float(__builtin_amdgcn_readfirstlane(__float_as_int(v)));
}
__device__ __forceinline__ float bcast_lane(float v, int srclane) {
    return __int_as_float(__builtin_amdgcn_readlane(__float_as_int(v), srclane));
}
__device__ __forceinline__ float sigm(float x) {
    return __builtin_amdgcn_rcpf(1.f + __expf(-x));
}
__device__ __forceinline__ float tanh_fast(float x) {
    float e = __expf(2.f * x);
    return 1.f - 2.f * __builtin_amdgcn_rcpf(e + 1.f);
}
__device__ __forceinline__ float sgnx(float v, unsigned m) {
    return __int_as_float(__float_as_int(v) ^ (int)m);
}

// SU(2) gate on a lane-bit qubit; u = {ax, ay(sign-baked), bx(sign-baked), by}.
template<int M>
__device__ __forceinline__ void gate_lane(float (&are)[4], float (&aim)[4], const float* u) {
#pragma unroll
    for (int r = 0; r < 4; ++r) {
        float px = lx<M>(are[r]);
        float py = lx<M>(aim[r]);
        float nx = u[0]*are[r] - u[1]*aim[r] + u[2]*px - u[3]*py;
        float ny = u[0]*aim[r] + u[1]*are[r] + u[2]*py + u[3]*px;
        are[r] = nx; aim[r] = ny;
    }
}

// SU(2) gate on a register-bit qubit pair.
__device__ __forceinline__ void gate_pair2(float& a0x, float& a0y, float& a1x, float& a1y,
                                           float ax, float ay, float bx, float by) {
    float n0x = ax*a0x - ay*a0y + bx*a1x - by*a1y;
    float n0y = ax*a0y + ay*a0x + bx*a1y + by*a1x;
    float n1x = -bx*a0x - by*a0y + ax*a1x + ay*a1y;
    float n1y = -bx*a0y + by*a0x + ax*a1y - ay*a1x;
    a0x = n0x; a0y = n0y; a1x = n1x; a1y = n1y;
}

__global__ __launch_bounds__(256, 1) void qlstm_kernel(Args a) {
    const int b    = blockIdx.x;
    const int tid  = threadIdx.x;
    const int lane = tid & 63;
    const int wv   = tid >> 6;          // wave id == gate id (f,i,g,o)

    __shared__ float Ax[TT][32];                       // x-part of angles (+bias), all t
    __shared__ __align__(16) float hH[16][HID];        // h history ring (flushed /16 steps)
    __shared__ __align__(16) float4 uab[4][2][8];      // SU(2) (ax,ay,bx,by) per gate
    __shared__ __align__(16) float expL[32];           // <Z_q> all 4 gates

    const int a_ang = tid >> 3, p = tid & 7;
    const int g_ang = a_ang >> 3, q_ang = a_ang & 7;
    float whr[8][4];
    {
        const float* Wg = a.W[g_ang] + q_ang * CD + IND;
#pragma unroll
        for (int k = 0; k < 8; ++k) {
            int base = p * 32 + ((4 * (k + p)) & 31);
#pragma unroll
            for (int j = 0; j < 4; ++j) whr[k][j] = Wg[base + j];
        }
    }
    float ur[4][8], cbr[4];
#pragma unroll
    for (int g = 0; g < 4; ++g) {
#pragma unroll
        for (int k = 0; k < 8; ++k) ur[g][k] = a.Uo[g][tid * 8 + k];
        cbr[g] = a.cb[g][tid];
    }

    // ---- SU(2) parameter unitaries alpha,beta = Rz*Ry*Rx (once) ----
    if (tid < 64) {
        int g = tid >> 4, d = (tid >> 3) & 1, q = tid & 7;
        const float* qp = a.qp[g] + q * 6 + d * 3;
        float s0, c0, s1, c1, s2, c2;
        sincosf(0.5f * qp[0], &s0, &c0);
        sincosf(0.5f * qp[1], &s1, &c1);
        sincosf(0.5f * qp[2], &s2, &c2);
        C2 aX{c0, 0.f}, bX{0.f, -s0};
        C2 aY{c1, 0.f}, bY{-s1, 0.f};
        C2 aB = csub(cmul(aY, aX), cmul(bY, conjc(bX)));
        C2 bB = cadd(cmul(aY, bX), cmul(bY, conjc(aX)));
        C2 aZ{c2, -s2};
        C2 al = cmul(aZ, aB), be = cmul(aZ, bB);
        uab[g][d][q] = make_float4(al.x, al.y, be.x, be.y);
    }

    // ---- x-part of angles for all timesteps (once) ----
    for (int rep = 0; rep < 8; ++rep) {
        int idx = rep * 256 + tid;
        int t = idx >> 5, aa = idx & 31;
        int gg = aa >> 3, qq = aa & 7;
        const float4* w4 = (const float4*)(a.W[gg] + qq * CD);
        const float4* x4 = (const float4*)(a.x + (size_t)(t * BB + b) * IND);
        float acc = a.bb[gg][qq];
        for (int e = 0; e < IND / 4; ++e) {
            float4 xv = x4[e], wvv = w4[e];
            acc += xv.x * wvv.x + xv.y * wvv.y + xv.z * wvv.z + xv.w * wvv.w;
        }
        Ax[t][aa] = acc;
    }

    hH[15][tid] = 0.f;
    float creg = 0.f, h = 0.f;
    __syncthreads();

    // ---- d=0 unitaries as uniform registers (for the init fold) ----
    float u0q[8][4];
#pragma unroll
    for (int q = 0; q < 8; ++q) {
        float4 u = uab[wv][0][q];
        u0q[q][0] = rfl(u.x); u0q[q][1] = rfl(u.y);
        u0q[q][2] = rfl(u.z); u0q[q][3] = rfl(u.w);
    }
    // ---- d=1 lane-gate unitaries, sign-baked per lane ----
    float gA[6][4];
#pragma unroll
    for (int qi = 0; qi < 6; ++qi) {
        float4 u = uab[wv][1][qi + 2];
        bool bit = (lane >> (5 - qi)) & 1;
        gA[qi][0] = u.x;
        gA[qi][1] = bit ? -u.y : u.y;
        gA[qi][2] = bit ? -u.z : u.z;
        gA[qi][3] = u.w;
    }
    float qr0[4], qr1[4];
    {
        float4 u0 = uab[wv][1][0], u1 = uab[wv][1][1];
        qr0[0] = rfl(u0.x); qr0[1] = rfl(u0.y); qr0[2] = rfl(u0.z); qr0[3] = rfl(u0.w);
        qr1[0] = rfl(u1.x); qr1[1] = rfl(u1.y); qr1[2] = rfl(u1.z); qr1[3] = rfl(u1.w);
    }

    // ---- d=0 CNOT chain folded into init: selector bits b = M^-1(p).
    // p0=r>>1, p1=r&1, p2..p7 = lane bits 5..0.
    // b0=p0^p7, b1=p1^p0^p7, bq=p(q-1)^pq (q>=2). Per-lane parts:
    const bool st3 = ((lane >> 4) ^ (lane >> 5)) & 1;   // b3
    const bool st4 = ((lane >> 3) ^ (lane >> 4)) & 1;   // b4
    const bool st5 = ((lane >> 2) ^ (lane >> 3)) & 1;   // b5
    const bool st6 = ((lane >> 1) ^ (lane >> 2)) & 1;   // b6
    const bool st7 = (lane ^ (lane >> 1)) & 1;          // b7
    const bool sp2 = (lane >> 5) & 1;                   // b2 = sp2 ^ (r&1)
    const bool sp7 = lane & 1;                          // enters b0, b1

    // ---- measurement sign masks (d=1 CNOT chain folded; proven R10) ----
    unsigned sg0, sg2, sg3, sg4, sg5, sg6, sg7;
    {
        auto par31 = [](int v) -> unsigned { return (unsigned)(__popc(v) & 1) << 31; };
        sg0 = par31(lane & 63);
        sg2 = par31(lane & 32);
        sg3 = par31(lane & 48);
        sg4 = par31(lane & 56);
        sg5 = par31(lane & 60);
        sg6 = par31(lane & 62);
        sg7 = sg0;
    }

    for (int t = 0; t < TT; ++t) {
        // ---- angle stage ----
        const int rowPrev = (t + 15) & 15;
        const float* hrow = hH[rowPrev];
        float ac0 = 0.f, ac1 = 0.f;
#pragma unroll
        for (int k = 0; k < 8; ++k) {
            int base = p * 32 + ((4 * (k + p)) & 31);
            const float4 hv = *reinterpret_cast<const float4*>(&hrow[base]);
            if (k & 1) { ac1 += hv.x*whr[k][0] + hv.y*whr[k][1] + hv.z*whr[k][2] + hv.w*whr[k][3]; }
            else       { ac0 += hv.x*whr[k][0] + hv.y*whr[k][1] + hv.z*whr[k][2] + hv.w*whr[k][3]; }
        }
        float acc = ac0 + ac1;
        acc += lx<1>(acc);
        acc += lx<2>(acc);
        acc += lx<4>(acc);
        float ang = 0.5f * (acc + Ax[t][a_ang]);
        float cA = __cosf(ang), sA = __sinf(ang);
        float cs_c[8], cs_s[8];
#pragma unroll
        for (int q = 0; q < 8; ++q) {
            cs_c[q] = bcast_lane(cA, q * 8);
            cs_s[q] = bcast_lane(sA, q * 8);
        }

        // ---- per-qubit 2-vectors with d=0 gates folded: v = U0 . (c, -i s) ----
        float v0x[8], v0y[8], v1x[8], v1y[8];
#pragma unroll
        for (int q = 0; q < 8; ++q) {
            float c = cs_c[q], s = cs_s[q];
            float ax = u0q[q][0], ay = u0q[q][1], bx = u0q[q][2], by = u0q[q][3];
            v0x[q] =  ax*c + by*s;
            v0y[q] =  ay*c - bx*s;
            v1x[q] = -bx*c - ay*s;
            v1y[q] =  by*c - ax*s;
        }

        // ---- init product evaluated at M^-1(p): d=0 CNOT chain folded away ----
        float are[4], aim[4];
        {
            C2 f3 = st3 ? C2{v1x[3], v1y[3]} : C2{v0x[3], v0y[3]};
            C2 f4 = st4 ? C2{v1x[4], v1y[4]} : C2{v0x[4], v0y[4]};
            C2 f5 = st5 ? C2{v1x[5], v1y[5]} : C2{v0x[5], v0y[5]};
            C2 f6 = st6 ? C2{v1x[6], v1y[6]} : C2{v0x[6], v0y[6]};
            C2 f7 = st7 ? C2{v1x[7], v1y[7]} : C2{v0x[7], v0y[7]};
            C2 common5 = cmul(cmul(cmul(f3, f4), cmul(f5, f6)), f7);
            C2 f2a = sp2 ? C2{v1x[2], v1y[2]} : C2{v0x[2], v0y[2]};   // b2 for r even
            C2 f2b = sp2 ? C2{v0x[2], v0y[2]} : C2{v1x[2], v1y[2]};   // b2 for r odd
            C2 c2a = cmul(common5, f2a);
            C2 c2b = cmul(common5, f2b);
            C2 f0a = sp7 ? C2{v1x[0], v1y[0]} : C2{v0x[0], v0y[0]};   // f0(p7)
            C2 f0b = sp7 ? C2{v0x[0], v0y[0]} : C2{v1x[0], v1y[0]};   // f0(!p7)
            C2 f1a = sp7 ? C2{v1x[1], v1y[1]} : C2{v0x[1], v0y[1]};   // f1(p7)
            C2 f1b = sp7 ? C2{v0x[1], v0y[1]} : C2{v1x[1], v1y[1]};   // f1(!p7)
            C2 uu = cmul(f1a, f0a);   // r=0: b1=p7,  b0=p7
            C2 m1 = cmul(f1b, f0a);   // r=1: b1=!p7, b0=p7
            C2 ww = cmul(f1b, f0b);   // r=2: b1=!p7, b0=!p7
            C2 m2 = cmul(f1a, f0b);   // r=3: b1=p7,  b0=!p7
            C2 a0 = cmul(c2a, uu), a1 = cmul(c2b, m1);
            C2 a2 = cmul(c2a, ww), a3 = cmul(c2b, m2);
            are[0] = a0.x; aim[0] = a0.y;
            are[1] = a1.x; aim[1] = a1.y;
            are[2] = a2.x; aim[2] = a2.y;
            are[3] = a3.x; aim[3] = a3.y;
        }

        // ---- d=1 gate layer (proven) ----
        gate_pair2(are[0], aim[0], are[2], aim[2], qr0[0], qr0[1], qr0[2], qr0[3]);
        gate_pair2(are[1], aim[1], are[3], aim[3], qr0[0], qr0[1], qr0[2], qr0[3]);
        gate_pair2(are[0], aim[0], are[1], aim[1], qr1[0], qr1[1], qr1[2], qr1[3]);
        gate_pair2(are[2], aim[2], are[3], aim[3], qr1[0], qr1[1], qr1[2], qr1[3]);
        gate_lane<32>(are, aim, gA[0]);
        gate_lane<16>(are, aim, gA[1]);
        gate_lane< 8>(are, aim, gA[2]);
        gate_lane< 4>(are, aim, gA[3]);
        gate_lane< 2>(are, aim, gA[4]);
        gate_lane< 1>(are, aim, gA[5]);

        // ---- expvals: signs (proven R10) + reduce-scatter butterfly ----
        float pr[4];
#pragma unroll
        for (int r = 0; r < 4; ++r) pr[r] = are[r]*are[r] + aim[r]*aim[r];
        float Bc = pr[0] - pr[1] + pr[2] - pr[3];
        float Dc = pr[0] - pr[1] - pr[2] + pr[3];
        float z[8];
        z[0] = sgnx(Bc, sg0);
        z[1] = Dc;
        z[2] = sgnx(Dc, sg2);
        z[3] = sgnx(Dc, sg3);
        z[4] = sgnx(Dc, sg4);
        z[5] = sgnx(Dc, sg5);
        z[6] = sgnx(Dc, sg6);
        z[7] = sgnx(Dc, sg7);
        // stage 1 (xor1): keep half by lane bit0 -> value-index bit2
        float w4a[4];
#pragma unroll
        for (int j = 0; j < 8; ++j) z[j] += lx<1>(z[j]);
#pragma unroll
        for (int j = 0; j < 4; ++j) w4a[j] = (lane & 1) ? z[j + 4] : z[j];
        // stage 2 (xor2): lane bit1 -> value-index bit1
        float w2a[2];
#pragma unroll
        for (int j = 0; j < 4; ++j) w4a[j] += lx<2>(w4a[j]);
#pragma unroll
        for (int j = 0; j < 2; ++j) w2a[j] = (lane & 2) ? w4a[j + 2] : w4a[j];
        // stage 3 (xor4): lane bit2 -> value-index bit0
        w2a[0] += lx<4>(w2a[0]);
        w2a[1] += lx<4>(w2a[1]);
        float wz = (lane & 4) ? w2a[1] : w2a[0];
        // stages 4-6: full adds on the single owned value
        wz += lx<8>(wz);
        wz += lx<16>(wz);
        wz += lx<32>(wz);
        // lane l<8 owns q = rev3(l) = (b0<<2)|(b1<<1)|b2
        if (lane < 8)
            expL[wv*8 + (((lane & 1) << 2) | (lane & 2) | ((lane >> 2) & 1))] = wz;
        __syncthreads();

        // ---- output projection + LSTM pointwise ----
        const float4* eL = (const float4*)expL;
        float og[4];
#pragma unroll
        for (int g = 0; g < 4; ++g) {
            float4 e0 = eL[g*2], e1 = eL[g*2 + 1];
            og[g] = cbr[g]
                  + e0.x*ur[g][0] + e0.y*ur[g][1] + e0.z*ur[g][2] + e0.w*ur[g][3]
                  + e1.x*ur[g][4] + e1.y*ur[g][5] + e1.z*ur[g][6] + e1.w*ur[g][7];
        }
        float fg = sigm(og[0]);
        float ig = sigm(og[1]);
        float gg = tanh_fast(og[2]);
        float oo = sigm(og[3]);
        creg = fg * creg + ig * gg;
        h = oo * tanh_fast(creg);

        hH[t & 15][tid] = h;
        if ((t & 15) == 15) {
            int t0 = t - 15;
#pragma unroll
            for (int r = 0; r < 16; ++r)
                a.out[(size_t)((t0 + r) * BB + b) * HID + tid] = hH[r][tid];
        }
        __syncthreads();
    }

    a.out[(size_t)TT * BB * HID + (size_t)b * HID + tid] = h;
    a.out[(size_t)TT * BB * HID + (size_t)BB * HID + (size_t)b * HID + tid] = creg;
}

extern "C" void kernel_launch(void* const* d_in, const int* in_sizes, int n_in,
                              void* d_out, int out_size, void* d_ws, size_t ws_size,
                              hipStream_t stream) {
    (void)in_sizes; (void)n_in; (void)out_size; (void)d_ws; (void)ws_size;
    Args ar;
    ar.x = (const float*)d_in[0];
    for (int g = 0; g < 4; ++g) {
        ar.W[g]  = (const float*)d_in[1 + 5 * g];
        ar.bb[g] = (const float*)d_in[2 + 5 * g];
        ar.qp[g] = (const float*)d_in[3 + 5 * g];
        ar.Uo[g] = (const float*)d_in[4 + 5 * g];
        ar.cb[g] = (const float*)d_in[5 + 5 * g];
    }
    ar.out = (float*)d_out;
    qlstm_kernel<<<dim3(BB), dim3(256), 0, stream>>>(ar);
}

// Round 12
// 131.149 us; speedup vs baseline: 1.2260x; 1.2260x over previous
//
#include <hip/hip_runtime.h>
#include <math.h>

#define BB   128
#define TT   64
#define IND  128
#define HID  256
#define CD   384   // comb dim = IND + HID

typedef float v2f __attribute__((ext_vector_type(2)));

struct C2 { float x, y; };
__device__ __forceinline__ C2 cmul(C2 a, C2 b) { return {a.x*b.x - a.y*b.y, a.x*b.y + a.y*b.x}; }
__device__ __forceinline__ C2 cadd(C2 a, C2 b) { return {a.x + b.x, a.y + b.y}; }
__device__ __forceinline__ C2 csub(C2 a, C2 b) { return {a.x - b.x, a.y - b.y}; }
__device__ __forceinline__ C2 conjc(C2 a) { return {a.x, -a.y}; }

__device__ __forceinline__ v2f pk(float a, float b) { v2f r; r.x = a; r.y = b; return r; }
__device__ __forceinline__ v2f swp(v2f v) { return __builtin_shufflevector(v, v, 1, 0); }

struct Args {
    const float* x;
    const float* W[4];
    const float* bb[4];
    const float* qp[4];
    const float* Uo[4];
    const float* cb[4];
    float* out;
};

template<int CTRL>
__device__ __forceinline__ int dppmv(int v) {
    return __builtin_amdgcn_update_dpp(v, v, CTRL, 0xF, 0xF, false);
}

// Lane-xor exchange (R9/R10-proven, all-VALU).
template<int M>
__device__ __forceinline__ float lx(float v) {
    int i = __float_as_int(v);
    if constexpr (M == 1)
        return __int_as_float(dppmv<0xB1>(i));            // quad_perm [1,0,3,2]
    else if constexpr (M == 2)
        return __int_as_float(dppmv<0x4E>(i));            // quad_perm [2,3,0,1]
    else if constexpr (M == 4) {
        int a = dppmv<0x104>(i);                          // row_shl:4
        int b = dppmv<0x114>(i);                          // row_shr:4
        return __int_as_float((threadIdx.x & 4) ? b : a);
    } else if constexpr (M == 8)
        return __int_as_float(dppmv<0x128>(i));           // row_ror:8 == xor8
    else if constexpr (M == 16) {
#if __has_builtin(__builtin_amdgcn_permlane16_swap)
        auto r = __builtin_amdgcn_permlane16_swap(i, i, false, false);
        return __int_as_float((threadIdx.x & 16) ? r[0] : r[1]);
#else
        return __int_as_float(__builtin_amdgcn_ds_swizzle(i, 0x401F));
#endif
    } else {
#if __has_builtin(__builtin_amdgcn_permlane32_swap)
        auto r = __builtin_amdgcn_permlane32_swap(i, i, false, false);
        return __int_as_float((threadIdx.x & 32) ? r[0] : r[1]);
#else
        return __shfl_xor(v, 32);
#endif
    }
}
template<int M>
__device__ __forceinline__ v2f lx2(v2f v) {
    return pk(lx<M>(v.x), lx<M>(v.y));
}

__device__ __forceinline__ float rfl(float v) {
    return __int_as_float(__builtin_amdgcn_readfirstlane(__float_as_int(v)));
}
__device__ __forceinline__ float bcast_lane(float v, int srclane) {
    return __int_as_float(__builtin_amdgcn_readlane(__float_as_int(v), srclane));
}
__device__ __forceinline__ float sigm(float x) {
    return __builtin_amdgcn_rcpf(1.f + __expf(-x));
}
__device__ __forceinline__ float tanh_fast(float x) {
    float e = __expf(2.f * x);
    return 1.f - 2.f * __builtin_amdgcn_rcpf(e + 1.f);
}
__device__ __forceinline__ float sgnx(float v, unsigned m) {
    return __int_as_float(__float_as_int(v) ^ (int)m);
}

// Packed SU(2) lane-gate on both reg-pairs; u0..u3 per-lane scalars (splat-broadcast).
template<int M>
__device__ __forceinline__ void gate_lane_pk(v2f& xe01, v2f& xi01, v2f& xe23, v2f& xi23,
                                             float u0, float u1, float u2, float u3) {
    v2f px0 = lx2<M>(xe01), py0 = lx2<M>(xi01);
    v2f px2 = lx2<M>(xe23), py2 = lx2<M>(xi23);
    v2f ne0 = u0*xe01 - u1*xi01 + u2*px0 - u3*py0;
    v2f ni0 = u0*xi01 + u1*xe01 + u2*py0 + u3*px0;
    v2f ne2 = u0*xe23 - u1*xi23 + u2*px2 - u3*py2;
    v2f ni2 = u0*xi23 + u1*xe23 + u2*py2 + u3*px2;
    xe01 = ne0; xi01 = ni0; xe23 = ne2; xi23 = ni2;
}

__global__ __launch_bounds__(256, 1) void qlstm_kernel(Args a) {
    const int b    = blockIdx.x;
    const int tid  = threadIdx.x;
    const int lane = tid & 63;
    const int wv   = tid >> 6;          // wave id == gate id (f,i,g,o)

    __shared__ float Ax[TT][32];                       // x-part of angles (+bias), all t
    __shared__ __align__(16) float hH[16][HID];        // h history ring (flushed /16 steps)
    __shared__ __align__(16) float4 uab[4][2][8];      // SU(2) (ax,ay,bx,by) per gate
    __shared__ __align__(16) float expL[32];           // <Z_q>, layout [q][gate]

    const int a_ang = tid >> 3, p = tid & 7;
    const int g_ang = a_ang >> 3, q_ang = a_ang & 7;
    v2f whr2[8][2];
    {
        const float* Wg = a.W[g_ang] + q_ang * CD + IND;
#pragma unroll
        for (int k = 0; k < 8; ++k) {
            int base = p * 32 + ((4 * (k + p)) & 31);
            whr2[k][0] = pk(Wg[base + 0], Wg[base + 1]);
            whr2[k][1] = pk(Wg[base + 2], Wg[base + 3]);
        }
    }
    // output-stage: pack U rows across gate pairs (f,i) and (g,o)
    v2f ur2a[8], ur2b[8], cb2a, cb2b;
#pragma unroll
    for (int k = 0; k < 8; ++k) {
        ur2a[k] = pk(a.Uo[0][tid * 8 + k], a.Uo[1][tid * 8 + k]);
        ur2b[k] = pk(a.Uo[2][tid * 8 + k], a.Uo[3][tid * 8 + k]);
    }
    cb2a = pk(a.cb[0][tid], a.cb[1][tid]);
    cb2b = pk(a.cb[2][tid], a.cb[3][tid]);

    // ---- SU(2) parameter unitaries alpha,beta = Rz*Ry*Rx (once) ----
    if (tid < 64) {
        int g = tid >> 4, d = (tid >> 3) & 1, q = tid & 7;
        const float* qp = a.qp[g] + q * 6 + d * 3;
        float s0, c0, s1, c1, s2, c2;
        sincosf(0.5f * qp[0], &s0, &c0);
        sincosf(0.5f * qp[1], &s1, &c1);
        sincosf(0.5f * qp[2], &s2, &c2);
        C2 aX{c0, 0.f}, bX{0.f, -s0};
        C2 aY{c1, 0.f}, bY{-s1, 0.f};
        C2 aB = csub(cmul(aY, aX), cmul(bY, conjc(bX)));
        C2 bB = cadd(cmul(aY, bX), cmul(bY, conjc(aX)));
        C2 aZ{c2, -s2};
        C2 al = cmul(aZ, aB), be = cmul(aZ, bB);
        uab[g][d][q] = make_float4(al.x, al.y, be.x, be.y);
    }

    // ---- x-part of angles for all timesteps (once) ----
    for (int rep = 0; rep < 8; ++rep) {
        int idx = rep * 256 + tid;
        int t = idx >> 5, aa = idx & 31;
        int gg = aa >> 3, qq = aa & 7;
        const float4* w4 = (const float4*)(a.W[gg] + qq * CD);
        const float4* x4 = (const float4*)(a.x + (size_t)(t * BB + b) * IND);
        float acc = a.bb[gg][qq];
        for (int e = 0; e < IND / 4; ++e) {
            float4 xv = x4[e], wvv = w4[e];
            acc += xv.x * wvv.x + xv.y * wvv.y + xv.z * wvv.z + xv.w * wvv.w;
        }
        Ax[t][aa] = acc;
    }

    hH[15][tid] = 0.f;
    float creg = 0.f, h = 0.f;
    __syncthreads();

    // ---- d=0 unitaries prepacked for the v-build:
    // Vx = pA*c + pB*s = (v0x, v1x); Vy = pC*c + pD*s = (v0y, v1y)
    v2f pA[8], pB[8], pC[8], pD[8];
#pragma unroll
    for (int q = 0; q < 8; ++q) {
        float4 u = uab[wv][0][q];
        float ax = rfl(u.x), ay = rfl(u.y), bx = rfl(u.z), by = rfl(u.w);
        pA[q] = pk(ax, -bx);
        pB[q] = pk(by, -ay);
        pC[q] = pk(ay, by);
        pD[q] = pk(-bx, -ax);
    }
    // ---- d=1 lane-gate unitaries, sign-baked per lane (scalars, splat in pk ops) ----
    float gA[6][4];
#pragma unroll
    for (int qi = 0; qi < 6; ++qi) {
        float4 u = uab[wv][1][qi + 2];
        bool bit = (lane >> (5 - qi)) & 1;
        gA[qi][0] = u.x;
        gA[qi][1] = bit ? -u.y : u.y;
        gA[qi][2] = bit ? -u.z : u.z;
        gA[qi][3] = u.w;
    }
    // ---- d=1 reg-gate unitaries (uniform scalars + mixed-sign packs for qubit1) ----
    float q0ax, q0ay, q0bx, q0by;
    float q1ax, q1by;
    v2f q1aym, q1ayp, q1bxm;
    {
        float4 u0 = uab[wv][1][0], u1 = uab[wv][1][1];
        q0ax = rfl(u0.x); q0ay = rfl(u0.y); q0bx = rfl(u0.z); q0by = rfl(u0.w);
        q1ax = rfl(u1.x); q1by = rfl(u1.w);
        float ay = rfl(u1.y), bx = rfl(u1.z);
        q1aym = pk(-ay, ay);
        q1ayp = pk(ay, -ay);
        q1bxm = pk(bx, -bx);
    }

    // ---- d=0 CNOT chain folded into init (proven R11): selector bits ----
    const bool st3 = ((lane >> 4) ^ (lane >> 5)) & 1;
    const bool st4 = ((lane >> 3) ^ (lane >> 4)) & 1;
    const bool st5 = ((lane >> 2) ^ (lane >> 3)) & 1;
    const bool st6 = ((lane >> 1) ^ (lane >> 2)) & 1;
    const bool st7 = (lane ^ (lane >> 1)) & 1;
    const bool sp2 = (lane >> 5) & 1;
    const bool sp7 = lane & 1;

    // ---- measurement sign masks (proven R10) ----
    unsigned sg0, sg2, sg3, sg4, sg5, sg6, sg7;
    {
        auto par31 = [](int v) -> unsigned { return (unsigned)(__popc(v) & 1) << 31; };
        sg0 = par31(lane & 63);
        sg2 = par31(lane & 32);
        sg3 = par31(lane & 48);
        sg4 = par31(lane & 56);
        sg5 = par31(lane & 60);
        sg6 = par31(lane & 62);
        sg7 = sg0;
    }

    for (int t = 0; t < TT; ++t) {
        // ---- angle stage (packed dot) ----
        const int rowPrev = (t + 15) & 15;
        const float* hrow = hH[rowPrev];
        v2f acc2 = pk(0.f, 0.f);
#pragma unroll
        for (int k = 0; k < 8; ++k) {
            int base = p * 32 + ((4 * (k + p)) & 31);
            const float4 hv = *reinterpret_cast<const float4*>(&hrow[base]);
            acc2 = acc2 + pk(hv.x, hv.y) * whr2[k][0] + pk(hv.z, hv.w) * whr2[k][1];
        }
        float acc = acc2.x + acc2.y;
        acc += lx<1>(acc);
        acc += lx<2>(acc);
        acc += lx<4>(acc);
        float ang = 0.5f * (acc + Ax[t][a_ang]);
        float cA = __cosf(ang), sA = __sinf(ang);
        float cs_c[8], cs_s[8];
#pragma unroll
        for (int q = 0; q < 8; ++q) {
            cs_c[q] = bcast_lane(cA, q * 8);
            cs_s[q] = bcast_lane(sA, q * 8);
        }

        // ---- packed v-build: Vx[q]=(v0x,v1x), Vy[q]=(v0y,v1y) ----
        v2f Vx[8], Vy[8];
#pragma unroll
        for (int q = 0; q < 8; ++q) {
            Vx[q] = pA[q] * cs_c[q] + pB[q] * cs_s[q];
            Vy[q] = pC[q] * cs_c[q] + pD[q] * cs_s[q];
        }

        // ---- init product at M^-1(p) (d=0 CNOT folded; tree part-packed) ----
        v2f xe01, xi01, xe23, xi23;
        {
            C2 f3{ st3 ? Vx[3].y : Vx[3].x, st3 ? Vy[3].y : Vy[3].x };
            C2 f4{ st4 ? Vx[4].y : Vx[4].x, st4 ? Vy[4].y : Vy[4].x };
            C2 f5{ st5 ? Vx[5].y : Vx[5].x, st5 ? Vy[5].y : Vy[5].x };
            C2 f6{ st6 ? Vx[6].y : Vx[6].x, st6 ? Vy[6].y : Vy[6].x };
            C2 f7{ st7 ? Vx[7].y : Vx[7].x, st7 ? Vy[7].y : Vy[7].x };
            C2 c5 = cmul(cmul(cmul(f3, f4), cmul(f5, f6)), f7);
            // f2 pair (r even, r odd): (f2a, f2b) = sp2 ? (v1,v0) : (v0,v1)
            v2f f2re = sp2 ? swp(Vx[2]) : Vx[2];
            v2f f2im = sp2 ? swp(Vy[2]) : Vy[2];
            // c2pair = c5 * f2pair
            v2f c2re = c5.x * f2re - c5.y * f2im;
            v2f c2im = c5.x * f2im + c5.y * f2re;
            // f1 pair (f1a, f1b) = sp7 ? (v1,v0) : (v0,v1); f0a/f0b scalars
            v2f f1re = sp7 ? swp(Vx[1]) : Vx[1];
            v2f f1im = sp7 ? swp(Vy[1]) : Vy[1];
            float f0ax = sp7 ? Vx[0].y : Vx[0].x, f0ay = sp7 ? Vy[0].y : Vy[0].x;
            float f0bx = sp7 ? Vx[0].x : Vx[0].y, f0by = sp7 ? Vy[0].x : Vy[0].y;
            // (uu,m1) = f1pair * f0a ; (ww,m2) = swap(f1pair) * f0b
            v2f uure = f1re * f0ax - f1im * f0ay;
            v2f uuim = f1re * f0ay + f1im * f0ax;
            v2f s1re = swp(f1re), s1im = swp(f1im);
            v2f wwre = s1re * f0bx - s1im * f0by;
            v2f wwim = s1re * f0by + s1im * f0bx;
            // amps: (a0,a1) = c2pair*(uu,m1); (a2,a3) = c2pair*(ww,m2)
            xe01 = c2re * uure - c2im * uuim;
            xi01 = c2re * uuim + c2im * uure;
            xe23 = c2re * wwre - c2im * wwim;
            xi23 = c2re * wwim + c2im * wwre;
        }

        // ---- d=1 reg-gates (packed) ----
        { // qubit 0: pairs (0,2),(1,3) -> aligned across (01)/(23)
            v2f ne01 = q0ax*xe01 - q0ay*xi01 + q0bx*xe23 - q0by*xi23;
            v2f ni01 = q0ax*xi01 + q0ay*xe01 + q0bx*xi23 + q0by*xe23;
            v2f ne23 = -q0bx*xe01 - q0by*xi01 + q0ax*xe23 + q0ay*xi23;
            v2f ni23 = -q0bx*xi01 + q0by*xe01 + q0ax*xi23 - q0ay*xe23;
            xe01 = ne01; xi01 = ni01; xe23 = ne23; xi23 = ni23;
        }
        { // qubit 1: pairs (0,1),(2,3) -> within-pair via swap + mixed-sign packs
            v2f se01 = swp(xe01), si01 = swp(xi01);
            v2f se23 = swp(xe23), si23 = swp(xi23);
            v2f ne01 = q1ax*xe01 + q1aym*xi01 + q1bxm*se01 - q1by*si01;
            v2f ni01 = q1ax*xi01 + q1ayp*xe01 + q1bxm*si01 + q1by*se01;
            v2f ne23 = q1ax*xe23 + q1aym*xi23 + q1bxm*se23 - q1by*si23;
            v2f ni23 = q1ax*xi23 + q1ayp*xe23 + q1bxm*si23 + q1by*se23;
            xe01 = ne01; xi01 = ni01; xe23 = ne23; xi23 = ni23;
        }
        // ---- d=1 lane-gates (packed) ----
        gate_lane_pk<32>(xe01, xi01, xe23, xi23, gA[0][0], gA[0][1], gA[0][2], gA[0][3]);
        gate_lane_pk<16>(xe01, xi01, xe23, xi23, gA[1][0], gA[1][1], gA[1][2], gA[1][3]);
        gate_lane_pk< 8>(xe01, xi01, xe23, xi23, gA[2][0], gA[2][1], gA[2][2], gA[2][3]);
        gate_lane_pk< 4>(xe01, xi01, xe23, xi23, gA[3][0], gA[3][1], gA[3][2], gA[3][3]);
        gate_lane_pk< 2>(xe01, xi01, xe23, xi23, gA[4][0], gA[4][1], gA[4][2], gA[4][3]);
        gate_lane_pk< 1>(xe01, xi01, xe23, xi23, gA[5][0], gA[5][1], gA[5][2], gA[5][3]);

        // ---- expvals: sign masks + full butterfly (packed adds) ----
        v2f pr01 = xe01 * xe01 + xi01 * xi01;
        v2f pr23 = xe23 * xe23 + xi23 * xi23;
        float pr0 = pr01.x, pr1 = pr01.y, pr2 = pr23.x, pr3 = pr23.y;
        float Bc = pr0 - pr1 + pr2 - pr3;
        float Dc = pr0 - pr1 - pr2 + pr3;
        v2f zA = pk(sgnx(Bc, sg0), Dc);
        v2f zB = pk(sgnx(Dc, sg2), sgnx(Dc, sg3));
        v2f zC = pk(sgnx(Dc, sg4), sgnx(Dc, sg5));
        v2f zD = pk(sgnx(Dc, sg6), sgnx(Dc, sg7));
        zA = zA + lx2<1>(zA);  zB = zB + lx2<1>(zB);  zC = zC + lx2<1>(zC);  zD = zD + lx2<1>(zD);
        zA = zA + lx2<2>(zA);  zB = zB + lx2<2>(zB);  zC = zC + lx2<2>(zC);  zD = zD + lx2<2>(zD);
        zA = zA + lx2<4>(zA);  zB = zB + lx2<4>(zB);  zC = zC + lx2<4>(zC);  zD = zD + lx2<4>(zD);
        zA = zA + lx2<8>(zA);  zB = zB + lx2<8>(zB);  zC = zC + lx2<8>(zC);  zD = zD + lx2<8>(zD);
        zA = zA + lx2<16>(zA); zB = zB + lx2<16>(zB); zC = zC + lx2<16>(zC); zD = zD + lx2<16>(zD);
        zA = zA + lx2<32>(zA); zB = zB + lx2<32>(zB); zC = zC + lx2<32>(zC); zD = zD + lx2<32>(zD);
        if (lane == 0) {
            expL[0*4 + wv] = zA.x; expL[1*4 + wv] = zA.y;
            expL[2*4 + wv] = zB.x; expL[3*4 + wv] = zB.y;
            expL[4*4 + wv] = zC.x; expL[5*4 + wv] = zC.y;
            expL[6*4 + wv] = zD.x; expL[7*4 + wv] = zD.y;
        }
        __syncthreads();

        // ---- output projection (packed across gate pairs) + LSTM pointwise ----
        const float4* eL4 = (const float4*)expL;   // eL4[k] = (z_k gate0..3)
        v2f og2a = cb2a, og2b = cb2b;
#pragma unroll
        for (int k = 0; k < 8; ++k) {
            float4 e4 = eL4[k];
            og2a = og2a + pk(e4.x, e4.y) * ur2a[k];
            og2b = og2b + pk(e4.z, e4.w) * ur2b[k];
        }
        float fg = sigm(og2a.x);
        float ig = sigm(og2a.y);
        float gg = tanh_fast(og2b.x);
        float oo = sigm(og2b.y);
        creg = fg * creg + ig * gg;
        h = oo * tanh_fast(creg);

        hH[t & 15][tid] = h;
        if ((t & 15) == 15) {
            int t0 = t - 15;
#pragma unroll
            for (int r = 0; r < 16; ++r)
                a.out[(size_t)((t0 + r) * BB + b) * HID + tid] = hH[r][tid];
        }
        __syncthreads();
    }

    a.out[(size_t)TT * BB * HID + (size_t)b * HID + tid] = h;
    a.out[(size_t)TT * BB * HID + (size_t)BB * HID + (size_t)b * HID + tid] = creg;
}

extern "C" void kernel_launch(void* const* d_in, const int* in_sizes, int n_in,
                              void* d_out, int out_size, void* d_ws, size_t ws_size,
                              hipStream_t stream) {
    (void)in_sizes; (void)n_in; (void)out_size; (void)d_ws; (void)ws_size;
    Args ar;
    ar.x = (const float*)d_in[0];
    for (int g = 0; g < 4; ++g) {
        ar.W[g]  = (const float*)d_in[1 + 5 * g];
        ar.bb[g] = (const float*)d_in[2 + 5 * g];
        ar.qp[g] = (const float*)d_in[3 + 5 * g];
        ar.Uo[g] = (const float*)d_in[4 + 5 * g];
        ar.cb[g] = (const float*)d_in[5 + 5 * g];
    }
    ar.out = (float*)d_out;
    qlstm_kernel<<<dim3(BB), dim3(256), 0, stream>>>(ar);
}